// Round 1
// baseline (445.574 us; speedup 1.0000x reference)
//
#include <hip/hip_runtime.h>
#include <hip/hip_bf16.h>

// ---------------------------------------------------------------------------
// MultiLevelFeatureSampler: gather 83-tap multi-scale patches (7x7+5x5+3x3)
// around 2048 points over 128 channels, then FC 83 -> 256.
// Strategy: bf16 MFMA GEMM (threshold 5.5e-2 permits bf16 inputs; fp32 VALU
// would be compute-bound at >70us while memory floor is ~53us).
//   kernel 1: pack W into MFMA-B fragment layout, bf16, K padded 83->96.
//   kernel 2: per (point, channel-half) block: gather patch -> LDS bf16,
//             4 waves x (1 M-tile x 16 N-tiles x 3 K-steps) of
//             v_mfma_f32_16x16x32_bf16, bias + store fp32.
// ---------------------------------------------------------------------------

typedef __bf16 bf16x8 __attribute__((ext_vector_type(8)));
typedef float f32x4 __attribute__((ext_vector_type(4)));

#define C_TOT 128
#define NPTS  512
#define OUTD  256
#define DTOT  83     // 49 + 25 + 9
#define KPAD  96     // 3 k-steps of 32
#define PITCH 104    // LDS row pitch in bf16: 208 B -> 16B-aligned rows

// feat dims
#define H0 93
#define W0 305
#define H1 47
#define W1 153
#define H2 24
#define W2 77
#define STRIDE0 (H0*W0)  // 28365
#define STRIDE1 (H1*W1)  // 7191
#define STRIDE2 (H2*W2)  // 1848

// ---------------------------------------------------------------------------
// Pack W (256 x 83 fp32) into bf16 MFMA-B fragments:
// Wb[((s*16 + nt)*64 + lane)*8 + j] = W[n][k],
//   n = nt*16 + (lane&15), k = s*32 + (lane>>4)*8 + j, zero for k >= 83.
// Total 3*16*64*8 = 24576 bf16 = 48 KB in d_ws.
// ---------------------------------------------------------------------------
__global__ void pack_w_kernel(const float* __restrict__ W, __bf16* __restrict__ Wb) {
    int t = blockIdx.x * 256 + threadIdx.x;
    if (t >= 3 * 16 * 64) return;
    int lane = t & 63;
    int nt   = (t >> 6) & 15;
    int s    = t >> 10;
    int n    = nt * 16 + (lane & 15);
    int kbase = s * 32 + (lane >> 4) * 8;
    #pragma unroll
    for (int j = 0; j < 8; ++j) {
        int k = kbase + j;
        float v = (k < DTOT) ? W[n * DTOT + k] : 0.f;
        Wb[(size_t)t * 8 + j] = (__bf16)v;
    }
}

// ---------------------------------------------------------------------------
// Main fused kernel. Grid: (2 halves, 512 points, 4 batches), block 256.
// ---------------------------------------------------------------------------
__global__ __launch_bounds__(256) void sampler_kernel(
    const float* __restrict__ points,
    const float* __restrict__ f0,
    const float* __restrict__ f1,
    const float* __restrict__ f2,
    const __bf16* __restrict__ Wb,
    const float* __restrict__ bias,
    float* __restrict__ out) {

    __shared__ __align__(16) __bf16 a_lds[64 * PITCH];
    __shared__ int s_base[DTOT];
    __shared__ int s_lvl[DTOT];

    const int tid  = threadIdx.x;
    const int half = blockIdx.x;
    const int p    = blockIdx.y;
    const int b    = blockIdx.z;
    const int c0   = half * 64;

    // ---- phase 1: 83 sample offsets (one thread each) + zero K-pad ----
    if (tid < DTOT) {
        int d = tid, l, dd, ks;
        if (d < 49)      { l = 0; dd = d;      ks = 7; }
        else if (d < 74) { l = 1; dd = d - 49; ks = 5; }
        else             { l = 2; dd = d - 74; ks = 3; }
        const int Hs[3] = {H0, H1, H2};
        const int Ws[3] = {W0, W1, W2};
        int H  = Hs[l];
        int Wd = Ws[l];
        int jj = dd / ks - ks / 2;   // row offset (outer in meshgrid 'ij')
        int kk = dd % ks - ks / 2;   // col offset (inner)
        float px = points[((size_t)(b * NPTS) + p) * 2 + 0];
        float py = points[((size_t)(b * NPTS) + p) * 2 + 1];
        float x = fminf(fmaxf(px * (float)(Wd - 1), 0.f), (float)(Wd - 1));
        float y = fminf(fmaxf(py * (float)(H  - 1), 0.f), (float)(H  - 1));
        float oxf = fminf(fmaxf(x + (float)kk, 0.f), (float)(Wd - 1));
        float oyf = fminf(fmaxf(y + (float)jj, 0.f), (float)(H  - 1));
        int ox = (int)oxf;   // floor == trunc (non-negative)
        int oy = (int)oyf;
        s_base[d] = b * C_TOT * H * Wd + oy * Wd + ox;
        s_lvl[d]  = l;
    }
    // zero pad columns 83..95 (read by MFMA as K-pad)
    for (int i = tid; i < 64 * (KPAD - DTOT); i += 256) {
        int r  = i / (KPAD - DTOT);
        int cc = DTOT + (i - r * (KPAD - DTOT));
        a_lds[r * PITCH + cc] = (__bf16)0.f;
    }
    __syncthreads();

    // ---- phase 2: gather 64 channels x 83 taps -> LDS (bf16) ----
    #pragma unroll 4
    for (int idx = tid; idx < 64 * DTOT; idx += 256) {
        int c = idx / DTOT;
        int d = idx - c * DTOT;
        int l = s_lvl[d];
        const float* fp = (l == 0) ? f0 : (l == 1) ? f1 : f2;
        int stride = (l == 0) ? STRIDE0 : (l == 1) ? STRIDE1 : STRIDE2;
        float v = fp[(size_t)s_base[d] + (size_t)(c0 + c) * stride];
        a_lds[c * PITCH + d] = (__bf16)v;
    }
    __syncthreads();

    // ---- phase 3: 4 waves x (16 rows x 256 cols) MFMA GEMM ----
    const int wave = tid >> 6;
    const int lane = tid & 63;
    const int quad = lane >> 4;
    const int lrow = lane & 15;

    f32x4 acc[16] = {};

    #pragma unroll
    for (int s = 0; s < 3; ++s) {
        // A fragment: A[m = lane&15][k = quad*8 + j], m-tile = wave
        bf16x8 af = *reinterpret_cast<const bf16x8*>(
            &a_lds[(wave * 16 + lrow) * PITCH + s * 32 + quad * 8]);
        const bf16x8* bptr =
            reinterpret_cast<const bf16x8*>(Wb) + (size_t)(s * 16) * 64;
        #pragma unroll
        for (int t = 0; t < 16; ++t) {
            bf16x8 bf = bptr[t * 64 + lane];
            acc[t] = __builtin_amdgcn_mfma_f32_16x16x32_bf16(af, bf, acc[t], 0, 0, 0);
        }
    }

    // ---- epilogue: bias + store fp32 ----
    float bv[16];
    #pragma unroll
    for (int t = 0; t < 16; ++t) bv[t] = bias[t * 16 + lrow];

    // D layout: col = lane&15 (n within tile), row = quad*4 + reg (m within tile)
    size_t outBase =
        (((size_t)(b * NPTS + p) * C_TOT) + c0 + wave * 16 + quad * 4) * OUTD + lrow;
    #pragma unroll
    for (int t = 0; t < 16; ++t) {
        #pragma unroll
        for (int r = 0; r < 4; ++r) {
            out[outBase + (size_t)r * OUTD + t * 16] = acc[t][r] + bv[t];
        }
    }
}

extern "C" void kernel_launch(void* const* d_in, const int* in_sizes, int n_in,
                              void* d_out, int out_size, void* d_ws, size_t ws_size,
                              hipStream_t stream) {
    const float* points = (const float*)d_in[0];
    const float* f0     = (const float*)d_in[1];
    const float* f1     = (const float*)d_in[2];
    const float* f2     = (const float*)d_in[3];
    const float* W      = (const float*)d_in[4];
    const float* bias   = (const float*)d_in[5];
    float* out = (float*)d_out;
    __bf16* Wb = (__bf16*)d_ws;   // 48 KB scratch

    pack_w_kernel<<<dim3(12), dim3(256), 0, stream>>>(W, Wb);
    sampler_kernel<<<dim3(2, NPTS, 4), dim3(256), 0, stream>>>(
        points, f0, f1, f2, Wb, bias, out);
}

// Round 2
// 384.595 us; speedup vs baseline: 1.1586x; 1.1586x over previous
//
#include <hip/hip_runtime.h>
#include <hip/hip_bf16.h>

// ---------------------------------------------------------------------------
// MultiLevelFeatureSampler: gather 83-tap multi-scale patches (7x7+5x5+3x3)
// around 2048 points over 128 channels, then FC 83 -> 256 via bf16 MFMA.
// R2 changes vs R1 (which was latency-bound: 192us @ 2.27 TB/s, occ 23%):
//  - gather fully batched: 21 addresses -> 21 loads in flight -> 21 LDS
//    writes (was unroll-4 with a vmcnt wait every 4 loads)
//  - two N-passes of 8 accumulators (32 acc regs instead of 64) +
//    __launch_bounds__(256,4) -> target 4 waves/SIMD occupancy
//  - K-pad trick: Wb is zero for k>=83, so A-side col 83 may hold any finite
//    value (dummy gather item); only cols 84..95 are explicitly zeroed.
// ---------------------------------------------------------------------------

typedef __bf16 bf16x8 __attribute__((ext_vector_type(8)));
typedef float f32x4 __attribute__((ext_vector_type(4)));

#define C_TOT 128
#define NPTS  512
#define OUTD  256
#define DTOT  83     // 49 + 25 + 9
#define DPAD  84     // pad so 64*84 = 256*21 items exactly
#define KPAD  96     // 3 k-steps of 32
#define PITCH 104    // LDS row pitch in bf16: 208 B -> 16B-aligned rows
#define ITEMS 21     // gather items per thread

// feat dims
#define H0 93
#define W0 305
#define H1 47
#define W1 153
#define H2 24
#define W2 77
#define STRIDE0 (H0*W0)
#define STRIDE1 (H1*W1)
#define STRIDE2 (H2*W2)

// ---------------------------------------------------------------------------
// Pack W (256 x 83 fp32) into bf16 MFMA-B fragments:
// Wb[((s*16 + nt)*64 + lane)*8 + j] = W[n][k],
//   n = nt*16 + (lane&15), k = s*32 + (lane>>4)*8 + j, zero for k >= 83.
// ---------------------------------------------------------------------------
__global__ void pack_w_kernel(const float* __restrict__ W, __bf16* __restrict__ Wb) {
    int t = blockIdx.x * 256 + threadIdx.x;
    if (t >= 3 * 16 * 64) return;
    int lane = t & 63;
    int nt   = (t >> 6) & 15;
    int s    = t >> 10;
    int n    = nt * 16 + (lane & 15);
    int kbase = s * 32 + (lane >> 4) * 8;
    #pragma unroll
    for (int j = 0; j < 8; ++j) {
        int k = kbase + j;
        float v = (k < DTOT) ? W[n * DTOT + k] : 0.f;
        Wb[(size_t)t * 8 + j] = (__bf16)v;
    }
}

// ---------------------------------------------------------------------------
// Main fused kernel. Grid: (2 halves, 512 points, 4 batches), block 256.
// ---------------------------------------------------------------------------
__global__ __launch_bounds__(256, 4) void sampler_kernel(
    const float* __restrict__ points,
    const float* __restrict__ f0,
    const float* __restrict__ f1,
    const float* __restrict__ f2,
    const __bf16* __restrict__ Wb,
    const float* __restrict__ bias,
    float* __restrict__ out) {

    __shared__ __align__(16) __bf16 a_lds[64 * PITCH];
    __shared__ long long s_addr[DPAD];   // byte address of tap d, channel c0
    __shared__ int s_stride[DPAD];       // channel stride in bytes

    const int tid  = threadIdx.x;
    const int half = blockIdx.x;
    const int p    = blockIdx.y;
    const int b    = blockIdx.z;
    const int c0   = half * 64;

    // ---- phase 1: 84 tap base addresses (tap 83 = dummy, any finite) ----
    if (tid < DPAD) {
        if (tid == DTOT) {
            s_addr[tid]   = (long long)(uintptr_t)f0;  // valid finite load
            s_stride[tid] = 0;
        } else {
            int d = tid, l, dd, ks;
            if (d < 49)      { l = 0; dd = d;      ks = 7; }
            else if (d < 74) { l = 1; dd = d - 49; ks = 5; }
            else             { l = 2; dd = d - 74; ks = 3; }
            const int Hs[3] = {H0, H1, H2};
            const int Ws[3] = {W0, W1, W2};
            int H  = Hs[l];
            int Wd = Ws[l];
            int jj = dd / ks - ks / 2;   // row offset (outer)
            int kk = dd % ks - ks / 2;   // col offset (inner)
            float px = points[((size_t)(b * NPTS) + p) * 2 + 0];
            float py = points[((size_t)(b * NPTS) + p) * 2 + 1];
            float x = fminf(fmaxf(px * (float)(Wd - 1), 0.f), (float)(Wd - 1));
            float y = fminf(fmaxf(py * (float)(H  - 1), 0.f), (float)(H  - 1));
            float oxf = fminf(fmaxf(x + (float)kk, 0.f), (float)(Wd - 1));
            float oyf = fminf(fmaxf(y + (float)jj, 0.f), (float)(H  - 1));
            int ox = (int)oxf;           // floor == trunc (non-negative)
            int oy = (int)oyf;
            const float* fp = (l == 0) ? f0 : (l == 1) ? f1 : f2;
            int stride = (l == 0) ? STRIDE0 : (l == 1) ? STRIDE1 : STRIDE2;
            s_addr[tid] = (long long)(uintptr_t)fp +
                          4LL * ((long long)(b * C_TOT + c0) * stride + oy * Wd + ox);
            s_stride[tid] = 4 * stride;
        }
    }
    // zero K-pad cols 84..95 (must be finite: NaN*0 = NaN in MFMA)
    for (int i = tid; i < 64 * (KPAD - DPAD); i += 256) {
        int r  = i / (KPAD - DPAD);
        int cc = DPAD + (i - r * (KPAD - DPAD));
        a_lds[r * PITCH + cc] = (__bf16)0.f;
    }
    __syncthreads();

    // ---- phase 2: batched gather, 21 loads in flight per thread ----
    const float* ap[ITEMS];
    #pragma unroll
    for (int k = 0; k < ITEMS; ++k) {
        int idx = tid + k * 256;         // < 5376
        int c = idx / DPAD;              // 0..63
        int d = idx - c * DPAD;          // 0..83
        ap[k] = (const float*)(s_addr[d] + (long long)(c * s_stride[d]));
    }
    float v[ITEMS];
    #pragma unroll
    for (int k = 0; k < ITEMS; ++k) v[k] = *ap[k];
    #pragma unroll
    for (int k = 0; k < ITEMS; ++k) {
        int idx = tid + k * 256;
        int c = idx / DPAD;
        int d = idx - c * DPAD;
        a_lds[c * PITCH + d] = (__bf16)v[k];
    }
    __syncthreads();

    // ---- phase 3: 4 waves x (16 rows x 256 cols), two N-passes of 8 ----
    const int wave = tid >> 6;
    const int lane = tid & 63;
    const int quad = lane >> 4;
    const int lrow = lane & 15;

    bf16x8 af[3];
    #pragma unroll
    for (int s = 0; s < 3; ++s)
        af[s] = *reinterpret_cast<const bf16x8*>(
            &a_lds[(wave * 16 + lrow) * PITCH + s * 32 + quad * 8]);

    size_t rowBase =
        (((size_t)(b * NPTS + p) * C_TOT) + c0 + wave * 16 + quad * 4) * OUTD + lrow;

    #pragma unroll
    for (int np = 0; np < 2; ++np) {
        f32x4 acc[8] = {};
        #pragma unroll
        for (int s = 0; s < 3; ++s) {
            const bf16x8* bptr =
                reinterpret_cast<const bf16x8*>(Wb) + ((s * 16 + np * 8) * 64 + lane);
            #pragma unroll
            for (int t = 0; t < 8; ++t)
                acc[t] = __builtin_amdgcn_mfma_f32_16x16x32_bf16(af[s], bptr[t * 64],
                                                                 acc[t], 0, 0, 0);
        }
        #pragma unroll
        for (int t = 0; t < 8; ++t) {
            int nt = np * 8 + t;
            float bv = bias[nt * 16 + lrow];
            #pragma unroll
            for (int r = 0; r < 4; ++r)
                out[rowBase + (size_t)r * OUTD + nt * 16] = acc[t][r] + bv;
        }
    }
}

extern "C" void kernel_launch(void* const* d_in, const int* in_sizes, int n_in,
                              void* d_out, int out_size, void* d_ws, size_t ws_size,
                              hipStream_t stream) {
    const float* points = (const float*)d_in[0];
    const float* f0     = (const float*)d_in[1];
    const float* f1     = (const float*)d_in[2];
    const float* f2     = (const float*)d_in[3];
    const float* W      = (const float*)d_in[4];
    const float* bias   = (const float*)d_in[5];
    float* out = (float*)d_out;
    __bf16* Wb = (__bf16*)d_ws;   // 48 KB scratch

    pack_w_kernel<<<dim3(12), dim3(256), 0, stream>>>(W, Wb);
    sampler_kernel<<<dim3(2, NPTS, 4), dim3(256), 0, stream>>>(
        points, f0, f1, f2, Wb, bias, out);
}

// Round 3
// 384.354 us; speedup vs baseline: 1.1593x; 1.0006x over previous
//
#include <hip/hip_runtime.h>
#include <hip/hip_bf16.h>

// ---------------------------------------------------------------------------
// MultiLevelFeatureSampler: gather 83-tap multi-scale patches (7x7+5x5+3x3)
// around 2048 points over 128 channels, then FC 83 -> 256 via bf16 MFMA.
// R3 changes vs R2 (sampler ~130us est., floor ~68us):
//  - gather loop fuses address-compute + load per item: address VGPRs are
//    transient (dead after load issue); only the 21 load dests stay live.
//    R2 kept 21 pointer pairs (42 VGPRs) + 21 dests live -> pressure/spill
//    under the launch_bounds(256,4) 128-VGPR cap.
//  - tap addresses stored as 32-bit BYTE offsets in LDS (ds_read_b32, not
//    b64); per-item address = base_l + off32[d] + c*stride_l  (all u32,
//    element indices fit 24 bits; c*stride <= 1.8M).
// ---------------------------------------------------------------------------

typedef __bf16 bf16x8 __attribute__((ext_vector_type(8)));
typedef float f32x4 __attribute__((ext_vector_type(4)));

#define C_TOT 128
#define NPTS  512
#define OUTD  256
#define DTOT  83     // 49 + 25 + 9
#define DPAD  84     // pad so 64*84 = 256*21 items exactly
#define KPAD  96     // 3 k-steps of 32
#define PITCH 104    // LDS row pitch in bf16: 208 B -> 16B-aligned rows
#define ITEMS 21     // gather items per thread

// feat dims
#define H0 93
#define W0 305
#define H1 47
#define W1 153
#define H2 24
#define W2 77
#define STRIDE0 (H0*W0)
#define STRIDE1 (H1*W1)
#define STRIDE2 (H2*W2)

// ---------------------------------------------------------------------------
// Pack W (256 x 83 fp32) into bf16 MFMA-B fragments:
// Wb[((s*16 + nt)*64 + lane)*8 + j] = W[n][k],
//   n = nt*16 + (lane&15), k = s*32 + (lane>>4)*8 + j, zero for k >= 83.
// ---------------------------------------------------------------------------
__global__ void pack_w_kernel(const float* __restrict__ W, __bf16* __restrict__ Wb) {
    int t = blockIdx.x * 256 + threadIdx.x;
    if (t >= 3 * 16 * 64) return;
    int lane = t & 63;
    int nt   = (t >> 6) & 15;
    int s    = t >> 10;
    int n    = nt * 16 + (lane & 15);
    int kbase = s * 32 + (lane >> 4) * 8;
    #pragma unroll
    for (int j = 0; j < 8; ++j) {
        int k = kbase + j;
        float v = (k < DTOT) ? W[n * DTOT + k] : 0.f;
        Wb[(size_t)t * 8 + j] = (__bf16)v;
    }
}

// ---------------------------------------------------------------------------
// Main fused kernel. Grid: (2 halves, 512 points, 4 batches), block 256.
// ---------------------------------------------------------------------------
__global__ __launch_bounds__(256, 4) void sampler_kernel(
    const float* __restrict__ points,
    const float* __restrict__ f0,
    const float* __restrict__ f1,
    const float* __restrict__ f2,
    const __bf16* __restrict__ Wb,
    const float* __restrict__ bias,
    float* __restrict__ out) {

    __shared__ __align__(16) __bf16 a_lds[64 * PITCH];
    __shared__ unsigned s_off[DPAD];   // byte offset of tap d at channel c0
                                       // within its level's buffer

    const int tid  = threadIdx.x;
    const int half = blockIdx.x;
    const int p    = blockIdx.y;
    const int b    = blockIdx.z;
    const int c0   = half * 64;

    // ---- phase 1: 84 tap byte-offsets (tap 83 = dummy -> f2[ c*stride2 ]) ----
    if (tid < DPAD) {
        if (tid == DTOT) {
            s_off[tid] = 0u;
        } else {
            int d = tid, l, dd, ks;
            if (d < 49)      { l = 0; dd = d;      ks = 7; }
            else if (d < 74) { l = 1; dd = d - 49; ks = 5; }
            else             { l = 2; dd = d - 74; ks = 3; }
            const int Hs[3] = {H0, H1, H2};
            const int Ws[3] = {W0, W1, W2};
            int H  = Hs[l];
            int Wd = Ws[l];
            int jj = dd / ks - ks / 2;   // row offset (outer)
            int kk = dd % ks - ks / 2;   // col offset (inner)
            float px = points[((size_t)(b * NPTS) + p) * 2 + 0];
            float py = points[((size_t)(b * NPTS) + p) * 2 + 1];
            float x = fminf(fmaxf(px * (float)(Wd - 1), 0.f), (float)(Wd - 1));
            float y = fminf(fmaxf(py * (float)(H  - 1), 0.f), (float)(H  - 1));
            float oxf = fminf(fmaxf(x + (float)kk, 0.f), (float)(Wd - 1));
            float oyf = fminf(fmaxf(y + (float)jj, 0.f), (float)(H  - 1));
            int ox = (int)oxf;           // floor == trunc (non-negative)
            int oy = (int)oyf;
            int stride = (l == 0) ? STRIDE0 : (l == 1) ? STRIDE1 : STRIDE2;
            // max elem index ~14.5M < 2^24; byte offset < 2^26 -> u32 safe
            s_off[tid] = 4u * (unsigned)((b * C_TOT + c0) * stride + oy * Wd + ox);
        }
    }
    // zero K-pad cols 84..95 (must be finite: NaN*0 = NaN in MFMA)
    for (int i = tid; i < 64 * (KPAD - DPAD); i += 256) {
        int r  = i / (KPAD - DPAD);
        int cc = DPAD + (i - r * (KPAD - DPAD));
        a_lds[r * PITCH + cc] = (__bf16)0.f;
    }
    __syncthreads();

    // ---- phase 2: gather, addr-compute fused with load (21 in flight) ----
    float v[ITEMS];
    #pragma unroll
    for (int k = 0; k < ITEMS; ++k) {
        int idx = tid + k * 256;          // < 5376
        int c = idx / DPAD;               // 0..63
        int d = idx - c * DPAD;           // 0..83
        unsigned off = s_off[d];
        bool ge1 = d >= 49, ge2 = d >= 74;
        unsigned strideb = ge2 ? 4u * STRIDE2 : (ge1 ? 4u * STRIDE1 : 4u * STRIDE0);
        const char* base = ge2 ? (const char*)f2 : (ge1 ? (const char*)f1
                                                        : (const char*)f0);
        v[k] = *(const float*)(base + (off + (unsigned)c * strideb));
    }
    #pragma unroll
    for (int k = 0; k < ITEMS; ++k) {
        int idx = tid + k * 256;
        int c = idx / DPAD;
        int d = idx - c * DPAD;
        a_lds[c * PITCH + d] = (__bf16)v[k];
    }
    __syncthreads();

    // ---- phase 3: 4 waves x (16 rows x 256 cols), two N-passes of 8 ----
    const int wave = tid >> 6;
    const int lane = tid & 63;
    const int quad = lane >> 4;
    const int lrow = lane & 15;

    bf16x8 af[3];
    #pragma unroll
    for (int s = 0; s < 3; ++s)
        af[s] = *reinterpret_cast<const bf16x8*>(
            &a_lds[(wave * 16 + lrow) * PITCH + s * 32 + quad * 8]);

    size_t rowBase =
        (((size_t)(b * NPTS + p) * C_TOT) + c0 + wave * 16 + quad * 4) * OUTD + lrow;

    #pragma unroll
    for (int np = 0; np < 2; ++np) {
        f32x4 acc[8] = {};
        #pragma unroll
        for (int s = 0; s < 3; ++s) {
            const bf16x8* bptr =
                reinterpret_cast<const bf16x8*>(Wb) + ((s * 16 + np * 8) * 64 + lane);
            #pragma unroll
            for (int t = 0; t < 8; ++t)
                acc[t] = __builtin_amdgcn_mfma_f32_16x16x32_bf16(af[s], bptr[t * 64],
                                                                 acc[t], 0, 0, 0);
        }
        #pragma unroll
        for (int t = 0; t < 8; ++t) {
            int nt = np * 8 + t;
            float bv = bias[nt * 16 + lrow];
            #pragma unroll
            for (int r = 0; r < 4; ++r)
                out[rowBase + (size_t)r * OUTD + nt * 16] = acc[t][r] + bv;
        }
    }
}

extern "C" void kernel_launch(void* const* d_in, const int* in_sizes, int n_in,
                              void* d_out, int out_size, void* d_ws, size_t ws_size,
                              hipStream_t stream) {
    const float* points = (const float*)d_in[0];
    const float* f0     = (const float*)d_in[1];
    const float* f1     = (const float*)d_in[2];
    const float* f2     = (const float*)d_in[3];
    const float* W      = (const float*)d_in[4];
    const float* bias   = (const float*)d_in[5];
    float* out = (float*)d_out;
    __bf16* Wb = (__bf16*)d_ws;   // 48 KB scratch

    pack_w_kernel<<<dim3(12), dim3(256), 0, stream>>>(W, Wb);
    sampler_kernel<<<dim3(2, NPTS, 4), dim3(256), 0, stream>>>(
        points, f0, f1, f2, Wb, bias, out);
}